// Round 15
// baseline (42.404 us; speedup 1.0000x reference)
//
#include <hip/hip_runtime.h>

// vol [2,160,192,160,1] f32, trf [2,160,192,160,3] f32
constexpr int B = 2, X = 160, Y = 192, Z = 160;
constexpr int TXs = 8, TYs = 8, TZs = 16;                // output tile per block (1024 voxels)
constexpr int XT = X / TXs, YT = Y / TYs, ZT = Z / TZs;  // 20, 24, 10
constexpr int NTILES = B * XT * YT * ZT;                 // 9600, divisible by 8
constexpr int NXCD = 8;
constexpr int CHUNK = NTILES / NXCD;                     // 1200
// staged region: x halo -4/+2 (15), y halo +-4 (16), z halo +-4 (24)
// layout: [row = ux*16+uy][uz], row stride 27 words. Conflicts are dominated
// by random-jitter collisions (layout-invariant, measured R10-R13) -- accepted.
constexpr int RX = 15, RY = 16, RZ = 24;
constexpr int RSTRIDE = 27;
constexpr int NROWS = RX * RY;                           // 240
constexpr int LDSF = NROWS * RSTRIDE;                    // 6480 words = 25920 B
constexpr int NCHUNKS = NROWS * 6;                       // 1440 f32x4 staging chunks

typedef float f32x4 __attribute__((ext_vector_type(4)));
typedef float f32x2a __attribute__((ext_vector_type(2), aligned(4)));

__global__ __launch_bounds__(512, 8) void warp_kernel(
    const float* __restrict__ vol,
    const float* __restrict__ trf,
    float* __restrict__ out)
{
    __shared__ float lds[LDSF];

    const int tid = threadIdx.x;
    const int bid = blockIdx.x;

    // XCD-chunked bijective swizzle (NTILES % 8 == 0)
    const int eff = (bid & (NXCD - 1)) * CHUNK + (bid >> 3);

    int tz = eff % ZT;
    int r  = eff / ZT;
    int ty = r % YT;
    int r2 = r / YT;
    int tx = r2 % XT;
    int b  = r2 / XT;

    const int xs = tx * TXs - 4;       // region x origin (15 wide: -4..+10)
    const int ys = ty * TYs - 4;       // region y origin
    const int zs = tz * TZs - 4;       // region z origin (multiple of 4)
    const int bX = b * X;

    // ---- stage vol region into LDS ----
    // chunk c in [0,1440): row = c/6, j = c%6, z = zs+4j (clamped);
    // LDS words row*27 + 4j .. +3.  512 threads x 3 iterations (last guarded).
    {
        int row = (tid * 171) >> 10;       // tid/6: exact for tid <= 514
        int j   = tid - 6 * row;
#pragma unroll
        for (int k = 0; k < 3; ++k) {
            if (k < 2 || tid < NCHUNKS - 1024) {
                int xi = row >> 4;
                int yi = row & 15;
                int xg = min(max(xs + xi, 0), X - 1);
                int yg = min(max(ys + yi, 0), Y - 1);
                int zg = min(max(zs + 4 * j, 0), Z - 4);
                const f32x4 v = *reinterpret_cast<const f32x4*>(
                    vol + ((size_t)(bX + xg) * Y + yg) * Z + zg);
                int a = row * RSTRIDE + 4 * j;
                lds[a + 0] = v.x;
                lds[a + 1] = v.y;
                lds[a + 2] = v.z;
                lds[a + 3] = v.w;
            }
            // advance by 512 chunks: +85 rows, j += 2 (mod 6 with carry)
            int jn = j + 2;
            bool wrap = (jn >= 6);
            j   = wrap ? jn - 6 : jn;
            row += wrap ? 86 : 85;
        }
    }
    __syncthreads();

    // ---- this thread's 2 voxels: (x, y, z0v..z0v+1) ----
    int zq = tid & 7;
    int ly = (tid >> 3) & 7;
    int lx = tid >> 6;
    int x  = tx * TXs + lx;
    int y  = ty * TYs + ly;
    int z0v = tz * TZs + 2 * zq;

    size_t vid0 = ((size_t)(bX + x) * Y + y) * Z + z0v;

    // 6 trf floats (2 voxels x 3)
    const float* tb = trf + vid0 * 3;
    f32x4 ta = *reinterpret_cast<const f32x4*>(tb);
    f32x2a tc = *reinterpret_cast<const f32x2a*>(tb + 4);
    float d[6] = {ta.x, ta.y, ta.z, ta.w, tc.x, tc.y};

    const float mx = (float)(X - 1), my = (float)(Y - 1), mz = (float)(Z - 1);
    const float fxc = (float)x, fyc = (float)y;
    const float xsf = (float)xs, ysf = (float)ys, zsf = (float)zs;

    float res[2];
#pragma unroll
    for (int e = 0; e < 2; ++e) {
        float lxf = fxc + d[3 * e + 0];
        float lyf = fyc + d[3 * e + 1];
        float lzf = (float)(z0v + e) + d[3 * e + 2];

        // clamp via med3, then region-relative coords; floor handles the
        // (-1,0) sliver (trunc would alias it to 0 and wrongly pass the test).
        float rxf = __builtin_amdgcn_fmed3f(lxf, 0.0f, mx) - xsf;
        float ryf = __builtin_amdgcn_fmed3f(lyf, 0.0f, my) - ysf;
        float rzf = __builtin_amdgcn_fmed3f(lzf, 0.0f, mz) - zsf;

        float flx = floorf(rxf), fly = floorf(ryf), flz = floorf(rzf);
        int ux0 = (int)flx, uy0 = (int)fly, uz0 = (int)flz;
        float fx = rxf - flx, fy = ryf - fly, fz = rzf - flz;

        bool ok = ((unsigned)ux0 < (unsigned)(RX - 1)) &
                  ((unsigned)uy0 < (unsigned)(RY - 1)) &
                  ((unsigned)uz0 < (unsigned)(RZ - 1));

        float v000, v001, v010, v011, v100, v101, v110, v111;
        if (ok) {
            // one base; corners at word offsets {0, 27 (+y), 432 (+x), 459}
            int w = ((ux0 << 4) + uy0) * RSTRIDE + uz0;
            f32x2a p00 = *reinterpret_cast<const f32x2a*>(&lds[w]);
            f32x2a p01 = *reinterpret_cast<const f32x2a*>(&lds[w + RSTRIDE]);
            f32x2a p10 = *reinterpret_cast<const f32x2a*>(&lds[w + 16 * RSTRIDE]);
            f32x2a p11 = *reinterpret_cast<const f32x2a*>(&lds[w + 17 * RSTRIDE]);
            v000 = p00.x; v001 = p00.y;
            v010 = p01.x; v011 = p01.y;
            v100 = p10.x; v101 = p10.y;
            v110 = p11.x; v111 = p11.y;
        } else {
            int ix0 = ux0 + xs, iy0 = uy0 + ys, iz0 = uz0 + zs;
            // fallback recomputes from global coords (exact reference path)
            ix0 = min(max(ix0, 0), X - 1);
            iy0 = min(max(iy0, 0), Y - 1);
            iz0 = min(max(iz0, 0), Z - 1);
            int ix1 = min(ix0 + 1, X - 1);
            int iy1 = min(iy0 + 1, Y - 1);
            int iz1 = min(iz0 + 1, Z - 1);
            size_t g00 = ((size_t)(bX + ix0) * Y + iy0) * Z;
            size_t g01 = ((size_t)(bX + ix0) * Y + iy1) * Z;
            size_t g10 = ((size_t)(bX + ix1) * Y + iy0) * Z;
            size_t g11 = ((size_t)(bX + ix1) * Y + iy1) * Z;
            v000 = vol[g00 + iz0];
            v001 = vol[g00 + iz1];
            v010 = vol[g01 + iz0];
            v011 = vol[g01 + iz1];
            v100 = vol[g10 + iz0];
            v101 = vol[g10 + iz1];
            v110 = vol[g11 + iz0];
            v111 = vol[g11 + iz1];
        }

        // trilinear lerp (z innermost), exact under clamp coincidences
        float c00 = v000 + fz * (v001 - v000);
        float c01 = v010 + fz * (v011 - v010);
        float c10 = v100 + fz * (v101 - v100);
        float c11 = v110 + fz * (v111 - v110);
        float c0  = c00 + fy * (c01 - c00);
        float c1  = c10 + fy * (c11 - c10);
        res[e] = c0 + fx * (c1 - c0);
    }

    f32x2a o;
    o.x = res[0]; o.y = res[1];
    *reinterpret_cast<f32x2a*>(out + vid0) = o;
}

extern "C" void kernel_launch(void* const* d_in, const int* in_sizes, int n_in,
                              void* d_out, int out_size, void* d_ws, size_t ws_size,
                              hipStream_t stream) {
    const float* vol = (const float*)d_in[0];
    const float* trf = (const float*)d_in[1];
    float* out = (float*)d_out;

    warp_kernel<<<NTILES, 512, 0, stream>>>(vol, trf, out);
}

// Round 16
// 41.935 us; speedup vs baseline: 1.0112x; 1.0112x over previous
//
#include <hip/hip_runtime.h>

// vol [2,160,192,160,1] f32, trf [2,160,192,160,3] f32
constexpr int B = 2, X = 160, Y = 192, Z = 160;
constexpr int TXs = 8, TYs = 8, TZs = 16;                // output tile per block (1024 voxels)
constexpr int XT = X / TXs, YT = Y / TYs, ZT = Z / TZs;  // 20, 24, 10
constexpr int NTILES = B * XT * YT * ZT;                 // 9600, divisible by 8
constexpr int NXCD = 8;
constexpr int CHUNK = NTILES / NXCD;                     // 1200
// staged region: x halo -4/+2 (15), y halo +-4 (16), z halo +-8 (32)
// layout: [row = ux*16+uy][uz], row stride 33 words.
// Staging: 8 f32x4 chunks/row -> write bank = row + 4j + i: EXACTLY 2-way
// (perfect). Read bank = 16ux + uy + uz (R9's empirical-best: 5.5M).
constexpr int RX = 15, RY = 16, RZ = 32;
constexpr int RSTRIDE = 33;
constexpr int NROWS = RX * RY;                           // 240
constexpr int LDSF = NROWS * RSTRIDE;                    // 7920 words = 31680 B
constexpr int NCHUNKS = NROWS * 8;                       // 1920 f32x4 staging chunks

typedef float f32x4 __attribute__((ext_vector_type(4)));
typedef float f32x2a __attribute__((ext_vector_type(2), aligned(4)));

__global__ __launch_bounds__(512, 4) void warp_kernel(
    const float* __restrict__ vol,
    const float* __restrict__ trf,
    float* __restrict__ out)
{
    __shared__ float lds[LDSF];

    const int tid = threadIdx.x;
    const int bid = blockIdx.x;

    // XCD-chunked bijective swizzle (NTILES % 8 == 0)
    const int eff = (bid & (NXCD - 1)) * CHUNK + (bid >> 3);

    int tz = eff % ZT;
    int r  = eff / ZT;
    int ty = r % YT;
    int r2 = r / YT;
    int tx = r2 % XT;
    int b  = r2 / XT;

    const int xs = tx * TXs - 4;       // region x origin (15 wide: -4..+10)
    const int ys = ty * TYs - 4;       // region y origin
    const int zs = tz * TZs - 8;       // region z origin (multiple of 4)
    const int bX = b * X;

    // ---- stage vol region into LDS ----
    // chunk c in [0,1920): row = c>>3, j = c&7, z = zs+4j (clamped);
    // LDS words row*33 + 4j .. +3.  512 threads: 3 full iters + 1 guarded.
    {
        int row = tid >> 3;
        int j   = tid & 7;
#pragma unroll
        for (int k = 0; k < 4; ++k) {
            if (k < 3 || tid < NCHUNKS - 1536) {
                int xi = row >> 4;
                int yi = row & 15;
                int xg = min(max(xs + xi, 0), X - 1);
                int yg = min(max(ys + yi, 0), Y - 1);
                int zg = min(max(zs + 4 * j, 0), Z - 4);
                const f32x4 v = *reinterpret_cast<const f32x4*>(
                    vol + ((size_t)(bX + xg) * Y + yg) * Z + zg);
                int a = row * RSTRIDE + 4 * j;
                lds[a + 0] = v.x;
                lds[a + 1] = v.y;
                lds[a + 2] = v.z;
                lds[a + 3] = v.w;
            }
            row += 64;                 // +512 chunks = +64 rows, j unchanged
        }
    }
    __syncthreads();

    // ---- this thread's 2 voxels: (x, y, z0v..z0v+1) ----
    int zq = tid & 7;
    int ly = (tid >> 3) & 7;
    int lx = tid >> 6;
    int x  = tx * TXs + lx;
    int y  = ty * TYs + ly;
    int z0v = tz * TZs + 2 * zq;

    size_t vid0 = ((size_t)(bX + x) * Y + y) * Z + z0v;

    // 6 trf floats (2 voxels x 3)
    const float* tb = trf + vid0 * 3;
    f32x4 ta = *reinterpret_cast<const f32x4*>(tb);
    f32x2a tc = *reinterpret_cast<const f32x2a*>(tb + 4);
    float d[6] = {ta.x, ta.y, ta.z, ta.w, tc.x, tc.y};

    const float mx = (float)(X - 1), my = (float)(Y - 1), mz = (float)(Z - 1);
    const float fxc = (float)x, fyc = (float)y;
    const float xsf = (float)xs, ysf = (float)ys, zsf = (float)zs;

    float res[2];
#pragma unroll
    for (int e = 0; e < 2; ++e) {
        float lxf = fxc + d[3 * e + 0];
        float lyf = fyc + d[3 * e + 1];
        float lzf = (float)(z0v + e) + d[3 * e + 2];

        // clamp via med3, then region-relative coords; floor handles the
        // (-1,0) sliver exactly.
        float rxf = __builtin_amdgcn_fmed3f(lxf, 0.0f, mx) - xsf;
        float ryf = __builtin_amdgcn_fmed3f(lyf, 0.0f, my) - ysf;
        float rzf = __builtin_amdgcn_fmed3f(lzf, 0.0f, mz) - zsf;

        float flx = floorf(rxf), fly = floorf(ryf), flz = floorf(rzf);
        int ux0 = (int)flx, uy0 = (int)fly, uz0 = (int)flz;
        float fx = rxf - flx, fy = ryf - fly, fz = rzf - flz;

        bool ok = ((unsigned)ux0 < (unsigned)(RX - 1)) &
                  ((unsigned)uy0 < (unsigned)(RY - 1)) &
                  ((unsigned)uz0 < (unsigned)(RZ - 1));

        float v000, v001, v010, v011, v100, v101, v110, v111;
        if (ok) {
            // one base; corners at word offsets {0, 33 (+y), 528 (+x), 561}
            int w = ((ux0 << 4) + uy0) * RSTRIDE + uz0;
            f32x2a p00 = *reinterpret_cast<const f32x2a*>(&lds[w]);
            f32x2a p01 = *reinterpret_cast<const f32x2a*>(&lds[w + RSTRIDE]);
            f32x2a p10 = *reinterpret_cast<const f32x2a*>(&lds[w + 16 * RSTRIDE]);
            f32x2a p11 = *reinterpret_cast<const f32x2a*>(&lds[w + 17 * RSTRIDE]);
            v000 = p00.x; v001 = p00.y;
            v010 = p01.x; v011 = p01.y;
            v100 = p10.x; v101 = p10.y;
            v110 = p11.x; v111 = p11.y;
        } else {
            int ix0 = ux0 + xs, iy0 = uy0 + ys, iz0 = uz0 + zs;
            ix0 = min(max(ix0, 0), X - 1);
            iy0 = min(max(iy0, 0), Y - 1);
            iz0 = min(max(iz0, 0), Z - 1);
            int ix1 = min(ix0 + 1, X - 1);
            int iy1 = min(iy0 + 1, Y - 1);
            int iz1 = min(iz0 + 1, Z - 1);
            size_t g00 = ((size_t)(bX + ix0) * Y + iy0) * Z;
            size_t g01 = ((size_t)(bX + ix0) * Y + iy1) * Z;
            size_t g10 = ((size_t)(bX + ix1) * Y + iy0) * Z;
            size_t g11 = ((size_t)(bX + ix1) * Y + iy1) * Z;
            v000 = vol[g00 + iz0];
            v001 = vol[g00 + iz1];
            v010 = vol[g01 + iz0];
            v011 = vol[g01 + iz1];
            v100 = vol[g10 + iz0];
            v101 = vol[g10 + iz1];
            v110 = vol[g11 + iz0];
            v111 = vol[g11 + iz1];
        }

        // trilinear lerp (z innermost), exact under clamp coincidences
        float c00 = v000 + fz * (v001 - v000);
        float c01 = v010 + fz * (v011 - v010);
        float c10 = v100 + fz * (v101 - v100);
        float c11 = v110 + fz * (v111 - v110);
        float c0  = c00 + fy * (c01 - c00);
        float c1  = c10 + fy * (c11 - c10);
        res[e] = c0 + fx * (c1 - c0);
    }

    f32x2a o;
    o.x = res[0]; o.y = res[1];
    *reinterpret_cast<f32x2a*>(out + vid0) = o;
}

extern "C" void kernel_launch(void* const* d_in, const int* in_sizes, int n_in,
                              void* d_out, int out_size, void* d_ws, size_t ws_size,
                              hipStream_t stream) {
    const float* vol = (const float*)d_in[0];
    const float* trf = (const float*)d_in[1];
    float* out = (float*)d_out;

    warp_kernel<<<NTILES, 512, 0, stream>>>(vol, trf, out);
}

// Round 17
// 40.955 us; speedup vs baseline: 1.0354x; 1.0239x over previous
//
#include <hip/hip_runtime.h>

// vol [2,160,192,160,1] f32, trf [2,160,192,160,3] f32
constexpr int B = 2, X = 160, Y = 192, Z = 160;
constexpr int TXs = 8, TYs = 8, TZs = 16;                // output tile per block (1024 voxels)
constexpr int XT = X / TXs, YT = Y / TYs, ZT = Z / TZs;  // 20, 24, 10
constexpr int NTILES = B * XT * YT * ZT;                 // 9600, divisible by 8
constexpr int NXCD = 8;
constexpr int CHUNK = NTILES / NXCD;                     // 1200
// staged region: x halo -4/+3 (15), y halo +-4 (16), z halo +-8 (32)
// layout: [row = ux*16+uy][uz], row stride 33 words.
// write bank = row + 4j + i: exactly 2-way (free). Residual read conflicts
// ~0.14 cy/instr (measured R15) -- accepted as floor.
constexpr int RX = 15, RY = 16, RZ = 32;
constexpr int RSTRIDE = 33;
constexpr int NROWS = RX * RY;                           // 240
constexpr int LDSF = NROWS * RSTRIDE;                    // 7920 words = 31680 B
constexpr int NCHUNKS = NROWS * 8;                       // 1920 f32x4 staging chunks

typedef float f32x4 __attribute__((ext_vector_type(4)));
typedef float f32x2a __attribute__((ext_vector_type(2), aligned(4)));

__global__ __launch_bounds__(512, 8) void warp_kernel(
    const float* __restrict__ vol,
    const float* __restrict__ trf,
    float* __restrict__ out)
{
    __shared__ float lds[LDSF];

    const int tid = threadIdx.x;
    const int bid = blockIdx.x;

    // XCD-chunked bijective swizzle (NTILES % 8 == 0)
    const int eff = (bid & (NXCD - 1)) * CHUNK + (bid >> 3);

    int tz = eff % ZT;
    int r  = eff / ZT;
    int ty = r % YT;
    int r2 = r / YT;
    int tx = r2 % XT;
    int b  = r2 / XT;

    const int xs = tx * TXs - 4;       // region x origin (15 wide: -4..+10)
    const int ys = ty * TYs - 4;       // region y origin
    const int zs = tz * TZs - 8;       // region z origin (multiple of 4)
    const int bX = b * X;

    // ---- stage vol region into LDS ----
    // chunk c in [0,1920): row = c>>3, j = c&7, z = zs+4j; LDS words row*33+4j..+3.
    // Interior blocks (no clamping anywhere): fully incremental addressing.
    {
        int row = tid >> 3;
        int j   = tid & 7;
        bool interior = (xs >= 0) & (xs + RX <= X) &
                        (ys >= 0) & (ys + RY <= Y) &
                        (zs >= 0) & (zs + RZ <= Z);
        if (interior) {
            const float* gp = vol +
                ((size_t)(bX + xs + (row >> 4)) * Y + (ys + (row & 15))) * Z
                + (zs + 4 * j);
            int a = row * RSTRIDE + 4 * j;
#pragma unroll
            for (int k = 0; k < 4; ++k) {
                if (k < 3 || tid < NCHUNKS - 1536) {
                    f32x4 v = *reinterpret_cast<const f32x4*>(gp);
                    lds[a + 0] = v.x;
                    lds[a + 1] = v.y;
                    lds[a + 2] = v.z;
                    lds[a + 3] = v.w;
                }
                gp += (size_t)4 * Y * Z;   // +64 rows = +4 x-slices
                a  += 64 * RSTRIDE;
            }
        } else {
#pragma unroll
            for (int k = 0; k < 4; ++k) {
                if (k < 3 || tid < NCHUNKS - 1536) {
                    int xi = row >> 4;
                    int yi = row & 15;
                    int xg = min(max(xs + xi, 0), X - 1);
                    int yg = min(max(ys + yi, 0), Y - 1);
                    int zg = min(max(zs + 4 * j, 0), Z - 4);
                    const f32x4 v = *reinterpret_cast<const f32x4*>(
                        vol + ((size_t)(bX + xg) * Y + yg) * Z + zg);
                    int a = row * RSTRIDE + 4 * j;
                    lds[a + 0] = v.x;
                    lds[a + 1] = v.y;
                    lds[a + 2] = v.z;
                    lds[a + 3] = v.w;
                }
                row += 64;
            }
        }
    }
    __syncthreads();

    // ---- this thread's 2 voxels: (x, y, z0v..z0v+1) ----
    int zq = tid & 7;
    int ly = (tid >> 3) & 7;
    int lx = tid >> 6;
    int x  = tx * TXs + lx;
    int y  = ty * TYs + ly;
    int z0v = tz * TZs + 2 * zq;

    size_t vid0 = ((size_t)(bX + x) * Y + y) * Z + z0v;

    // 6 trf floats (2 voxels x 3)
    const float* tb = trf + vid0 * 3;
    f32x4 ta = *reinterpret_cast<const f32x4*>(tb);
    f32x2a tc = *reinterpret_cast<const f32x2a*>(tb + 4);
    float d[6] = {ta.x, ta.y, ta.z, ta.w, tc.x, tc.y};

    // med3 shift-invariance: clip(g+disp,0,max)-origin
    //   = med3(local+disp, -origin, max-origin), local = g - origin.
    const float c0x = (float)(-xs), c1x = (float)(X - 1 - xs);
    const float c0y = (float)(-ys), c1y = (float)(Y - 1 - ys);
    const float c0z = (float)(-zs), c1z = (float)(Z - 1 - zs);
    const float fxL = (float)(lx + 4);       // x - xs
    const float fyL = (float)(ly + 4);       // y - ys
    const float fzL = (float)(2 * zq + 8);   // z0v - zs

    float res[2];
#pragma unroll
    for (int e = 0; e < 2; ++e) {
        float rxf = __builtin_amdgcn_fmed3f(fxL + d[3 * e + 0], c0x, c1x);
        float ryf = __builtin_amdgcn_fmed3f(fyL + d[3 * e + 1], c0y, c1y);
        float rzf = __builtin_amdgcn_fmed3f((fzL + (float)e) + d[3 * e + 2], c0z, c1z);

        float flx = floorf(rxf), fly = floorf(ryf), flz = floorf(rzf);
        int ux0 = (int)flx, uy0 = (int)fly, uz0 = (int)flz;
        float fx = rxf - flx, fy = ryf - fly, fz = rzf - flz;

        bool ok = ((unsigned)ux0 < (unsigned)(RX - 1)) &
                  ((unsigned)uy0 < (unsigned)(RY - 1)) &
                  ((unsigned)uz0 < (unsigned)(RZ - 1));

        float v000, v001, v010, v011, v100, v101, v110, v111;
        if (ok) {
            // one base; corners at word offsets {0, 33 (+y), 528 (+x), 561}
            int w = ((ux0 << 4) + uy0) * RSTRIDE + uz0;
            f32x2a p00 = *reinterpret_cast<const f32x2a*>(&lds[w]);
            f32x2a p01 = *reinterpret_cast<const f32x2a*>(&lds[w + RSTRIDE]);
            f32x2a p10 = *reinterpret_cast<const f32x2a*>(&lds[w + 16 * RSTRIDE]);
            f32x2a p11 = *reinterpret_cast<const f32x2a*>(&lds[w + 17 * RSTRIDE]);
            v000 = p00.x; v001 = p00.y;
            v010 = p01.x; v011 = p01.y;
            v100 = p10.x; v101 = p10.y;
            v110 = p11.x; v111 = p11.y;
        } else {
            int ix0 = ux0 + xs, iy0 = uy0 + ys, iz0 = uz0 + zs;
            ix0 = min(max(ix0, 0), X - 1);
            iy0 = min(max(iy0, 0), Y - 1);
            iz0 = min(max(iz0, 0), Z - 1);
            int ix1 = min(ix0 + 1, X - 1);
            int iy1 = min(iy0 + 1, Y - 1);
            int iz1 = min(iz0 + 1, Z - 1);
            size_t g00 = ((size_t)(bX + ix0) * Y + iy0) * Z;
            size_t g01 = ((size_t)(bX + ix0) * Y + iy1) * Z;
            size_t g10 = ((size_t)(bX + ix1) * Y + iy0) * Z;
            size_t g11 = ((size_t)(bX + ix1) * Y + iy1) * Z;
            v000 = vol[g00 + iz0];
            v001 = vol[g00 + iz1];
            v010 = vol[g01 + iz0];
            v011 = vol[g01 + iz1];
            v100 = vol[g10 + iz0];
            v101 = vol[g10 + iz1];
            v110 = vol[g11 + iz0];
            v111 = vol[g11 + iz1];
        }

        // trilinear lerp (z innermost), exact under clamp coincidences
        float c00 = v000 + fz * (v001 - v000);
        float c01 = v010 + fz * (v011 - v010);
        float c10 = v100 + fz * (v101 - v100);
        float c11 = v110 + fz * (v111 - v110);
        float c0  = c00 + fy * (c01 - c00);
        float c1  = c10 + fy * (c11 - c10);
        res[e] = c0 + fx * (c1 - c0);
    }

    f32x2a o;
    o.x = res[0]; o.y = res[1];
    *reinterpret_cast<f32x2a*>(out + vid0) = o;
}

extern "C" void kernel_launch(void* const* d_in, const int* in_sizes, int n_in,
                              void* d_out, int out_size, void* d_ws, size_t ws_size,
                              hipStream_t stream) {
    const float* vol = (const float*)d_in[0];
    const float* trf = (const float*)d_in[1];
    float* out = (float*)d_out;

    warp_kernel<<<NTILES, 512, 0, stream>>>(vol, trf, out);
}